// Round 8
// baseline (435.281 us; speedup 1.0000x reference)
//
#include <hip/hip_runtime.h>

#define T_DIM 4096
#define C_DIM 2048
#define K_DIM 2048

typedef __bf16 bf16x8 __attribute__((ext_vector_type(8)));
typedef float f32x4 __attribute__((ext_vector_type(4)));

__device__ __forceinline__ unsigned short f2bf(float f) {
  union { float f; unsigned int i; } x;
  x.f = f;
  unsigned int r = x.i + 0x7fffu + ((x.i >> 16) & 1u);  // round-to-nearest-even
  return (unsigned short)(r >> 16);
}

// async global->LDS, 16B per lane; LDS dest = wave-uniform base + lane*16
#define GLD16(gsrc, ldst)                                                   \
  __builtin_amdgcn_global_load_lds(                                         \
      (const __attribute__((address_space(1))) unsigned int*)(gsrc),        \
      (__attribute__((address_space(3))) unsigned int*)(ldst), 16, 0, 0)

// ---------------- W (K x N) fp32 -> Wt (N x K) bf16 ----------------
__global__ __launch_bounds__(256) void transpose_w(const float* __restrict__ W,
                                                   unsigned short* __restrict__ Wt) {
  __shared__ float tile[64][68];  // +4 pad
  const int c0 = blockIdx.x * 64;  // n
  const int r0 = blockIdx.y * 64;  // k
  const int tid = threadIdx.x;
#pragma unroll
  for (int i = 0; i < 4; ++i) {
    int s = tid + i * 256;  // 0..1023 float4 slots (64 rows x 16 slots)
    int r = s >> 4, c4 = (s & 15) * 4;
    *(float4*)&tile[r][c4] = *(const float4*)&W[(size_t)(r0 + r) * C_DIM + c0 + c4];
  }
  __syncthreads();
#pragma unroll
  for (int i = 0; i < 2; ++i) {
    int s = tid + i * 256;  // 0..511: 64 n-rows x 8 slots of 8 bf16
    int n = s >> 3, k8 = (s & 7) * 8;
    __align__(16) unsigned short tmp[8];
#pragma unroll
    for (int j = 0; j < 8; ++j) tmp[j] = f2bf(tile[k8 + j][n]);
    *(uint4*)&Wt[(size_t)(c0 + n) * K_DIM + r0 + k8] = *(uint4*)tmp;
  }
}

// ---------------- X fp32 -> Xb bf16 (one pass, RNE identical to f2bf staging) ----------------
__global__ __launch_bounds__(256) void cvt_x(const float* __restrict__ X,
                                             unsigned short* __restrict__ Xb) {
  size_t base = (size_t)blockIdx.x * 2048 + (size_t)threadIdx.x * 8;
  float4 a = *(const float4*)&X[base];
  float4 b = *(const float4*)&X[base + 4];
  __align__(16) unsigned short t[8];
  t[0] = f2bf(a.x); t[1] = f2bf(a.y); t[2] = f2bf(a.z); t[3] = f2bf(a.w);
  t[4] = f2bf(b.x); t[5] = f2bf(b.y); t[6] = f2bf(b.z); t[7] = f2bf(b.w);
  *(uint4*)&Xb[base] = *(const uint4*)t;
}

// -------- shared epilogue macros (reference locals of the enclosing kernel) --------
#define MFMA_OP(m,n) \
  a##m##n = __builtin_amdgcn_mfma_f32_16x16x32_bf16(af##m, bfr##n, a##m##n, 0, 0, 0);

#define LOADC(n)                                  \
  const int c##n = c_base + n * 16 + l16;         \
  const float hb##n = hhb[c##n];                  \
  const float gw##n = gnw[c##n];                  \
  const float gb##n = gnb[c##n];

#define ROPE_E(n,m,r)                                                   \
    { float v_ = a##m##n[r];                                            \
      float p_ = __shfl_xor(v_, 1, 64);                                 \
      int t_ = t_base + m * 16 + quad * 4 + r;                          \
      float ang_ = (float)t_ * fr_;                                     \
      float s_ = sinf(ang_);                                            \
      float co_ = cosf(ang_);                                           \
      a##m##n[r] = v_ * co_ + sg_ * p_ * s_; }
#define ROPE_M(n,m) ROPE_E(n,m,0) ROPE_E(n,m,1) ROPE_E(n,m,2) ROPE_E(n,m,3)

#define GN_ROW(m,r)                                                     \
  { float h0_ = tanhf(fmaxf(a##m##0[r], 0.f) + hb0);                    \
    float h1_ = tanhf(fmaxf(a##m##1[r], 0.f) + hb1);                    \
    float h2_ = tanhf(fmaxf(a##m##2[r], 0.f) + hb2);                    \
    float h3_ = tanhf(fmaxf(a##m##3[r], 0.f) + hb3);                    \
    float s1_ = h0_ + h1_ + h2_ + h3_;                                  \
    float s2_ = h0_ * h0_ + h1_ * h1_ + h2_ * h2_ + h3_ * h3_;          \
    s1_ += __shfl_xor(s1_, 1, 64);  s2_ += __shfl_xor(s2_, 1, 64);      \
    s1_ += __shfl_xor(s1_, 2, 64);  s2_ += __shfl_xor(s2_, 2, 64);      \
    s1_ += __shfl_xor(s1_, 4, 64);  s2_ += __shfl_xor(s2_, 4, 64);      \
    s1_ += __shfl_xor(s1_, 8, 64);  s2_ += __shfl_xor(s2_, 8, 64);      \
    float mu_ = s1_ * 0.015625f;                                        \
    float var_ = s2_ * 0.015625f - mu_ * mu_;                           \
    float rs_ = rsqrtf(var_ + 1e-5f);                                   \
    a##m##0[r] = (h0_ - mu_) * rs_ * gw0 + gb0;                         \
    a##m##1[r] = (h1_ - mu_) * rs_ * gw1 + gb1;                         \
    a##m##2[r] = (h2_ - mu_) * rs_ * gw2 + gb2;                         \
    a##m##3[r] = (h3_ - mu_) * rs_ * gw3 + gb3; }
#define GN_M(m) GN_ROW(m,0) GN_ROW(m,1) GN_ROW(m,2) GN_ROW(m,3)

// ======================= 256x256-tile bf16 fast path =======================
// 512 threads (8 waves: wm=wave>>2, wn=wave&3). Per wave: 128m x 64n (32 f32x4
// acc = 128 AGPR). 2 waves/SIMD -> hard 256-reg/wave cap, so the K-step is
// register-lean: B-frags once per kk (16 VGPR) + A-rows in two scoped groups
// of 4 (16 VGPR reused) -> peak frag regs 32 (round-7's 48 spilled: +107MB
// scratch writes). BK=64 dbuf (128KB LDS), counted vmcnt(8), raw barriers,
// bank-perfect XOR swizzle (row&7) on staging source and ds_read.
#define FOR_MN8(OP) \
  OP(0,0) OP(0,1) OP(0,2) OP(0,3) OP(1,0) OP(1,1) OP(1,2) OP(1,3) \
  OP(2,0) OP(2,1) OP(2,2) OP(2,3) OP(3,0) OP(3,1) OP(3,2) OP(3,3) \
  OP(4,0) OP(4,1) OP(4,2) OP(4,3) OP(5,0) OP(5,1) OP(5,2) OP(5,3) \
  OP(6,0) OP(6,1) OP(6,2) OP(6,3) OP(7,0) OP(7,1) OP(7,2) OP(7,3)
#define DECL_ACC8(m,n) f32x4 a##m##n = {0.f, 0.f, 0.f, 0.f};

#define LDS_LD(p) (*(const bf16x8*)(const void*)(p))
#define MFMA1(ar, f, bn) \
  a##ar##bn = __builtin_amdgcn_mfma_f32_16x16x32_bf16(f, b##bn, a##ar##bn, 0, 0, 0);
#define MFMA_R(ar, f) MFMA1(ar, f, 0) MFMA1(ar, f, 1) MFMA1(ar, f, 2) MFMA1(ar, f, 3)

// one kk half (K=32): 4 B-frags live, A-rows in two reg-reused groups of 4
#define KK_BLOCK(XS)                                                        \
  {                                                                         \
    bf16x8 b0 = LDS_LD(pb + bbase + 0 * 1024 + (XS));                       \
    bf16x8 b1 = LDS_LD(pb + bbase + 1 * 1024 + (XS));                       \
    bf16x8 b2 = LDS_LD(pb + bbase + 2 * 1024 + (XS));                       \
    bf16x8 b3 = LDS_LD(pb + bbase + 3 * 1024 + (XS));                       \
    {                                                                       \
      bf16x8 f0 = LDS_LD(pa + abase + 0 * 1024 + (XS));                     \
      bf16x8 f1 = LDS_LD(pa + abase + 1 * 1024 + (XS));                     \
      bf16x8 f2 = LDS_LD(pa + abase + 2 * 1024 + (XS));                     \
      bf16x8 f3 = LDS_LD(pa + abase + 3 * 1024 + (XS));                     \
      MFMA_R(0, f0) MFMA_R(1, f1) MFMA_R(2, f2) MFMA_R(3, f3)               \
    }                                                                       \
    {                                                                       \
      bf16x8 f4 = LDS_LD(pa + abase + 4 * 1024 + (XS));                     \
      bf16x8 f5 = LDS_LD(pa + abase + 5 * 1024 + (XS));                     \
      bf16x8 f6 = LDS_LD(pa + abase + 6 * 1024 + (XS));                     \
      bf16x8 f7 = LDS_LD(pa + abase + 7 * 1024 + (XS));                     \
      MFMA_R(4, f4) MFMA_R(5, f5) MFMA_R(6, f6) MFMA_R(7, f7)               \
    }                                                                       \
  }

__global__ __launch_bounds__(512, 2) void gemm_fused256(const unsigned short* __restrict__ Xb,
                                                        const unsigned short* __restrict__ Wt,
                                                        const float* __restrict__ hhb,
                                                        const float* __restrict__ gnw,
                                                        const float* __restrict__ gnb,
                                                        float* __restrict__ out) {
  __shared__ __align__(16) char smem[131072];             // 2x32KB A + 2x32KB B
  unsigned short* lsA = (unsigned short*)smem;            // [2][256][64] bf16
  unsigned short* lsB = (unsigned short*)(smem + 65536);  // [2][256][64] bf16
  float(*lsO)[68] = (float(*)[68])smem;                   // epilogue: [256][68] f32, 69.6KB

  const int tid = threadIdx.x;
  const int wave = tid >> 6;   // 0..7
  const int lane = tid & 63;
  const int quad = lane >> 4;
  const int l16 = lane & 15;
  const int wm = wave >> 2, wn = wave & 3;

  // XCD-aware: 256 blocks, XCD = bid&7 owns one n-column (B panel L2-resident)
  const int bid = blockIdx.x;
  const int wg = (bid & 7) * 32 + (bid >> 3);
  const int n0 = (wg >> 5) * 256;  // 8 n-blocks
  const int m0 = (wg & 31) * 256;  // 32 m-blocks

  FOR_MN8(DECL_ACC8)

  // staging: tile [256][64] shorts (128B rows); GLD16 covers 8 rows; wave w owns
  // rows [w*32, w*32+32) via 4 issues. lane -> row lane>>3, unit (lane&7)^(row&7).
  const int srow = lane >> 3;
  const int scol = ((lane & 7) ^ (srow & 7)) * 8;  // shorts
  const unsigned short* gA = Xb + (size_t)(m0 + wave * 32 + srow) * K_DIM + scol;
  const unsigned short* gB = Wt + (size_t)(n0 + wave * 32 + srow) * K_DIM + scol;

  // fragment reads: A row = wm*128 + mf*16 + l16, B row = wn*64 + nf*16 + l16;
  // row&7 == l16&7 -> xs = (kk*32 + quad*8) ^ ((l16&7)<<3)
  const int xs0 = (quad * 8) ^ ((l16 & 7) << 3);
  const int xs1 = (32 + quad * 8) ^ ((l16 & 7) << 3);
  const int abase = (wm * 128 + l16) * 64;  // + mf*1024 + xs
  const int bbase = (wn * 64 + l16) * 64;   // + nf*1024 + xs

  auto stage = [&](int d, int koff) {
#pragma unroll
    for (int r = 0; r < 4; ++r)
      GLD16(gA + (size_t)(r * 8) * K_DIM + koff, lsA + d * 16384 + wave * 2048 + r * 512);
#pragma unroll
    for (int r = 0; r < 4; ++r)
      GLD16(gB + (size_t)(r * 8) * K_DIM + koff, lsB + d * 16384 + wave * 2048 + r * 512);
  };

  constexpr int NT = K_DIM / 64;  // 32 K-tiles
  stage(0, 0);                    // prologue: tile 0 in flight
  for (int t = 0; t < NT; ++t) {
    const int cur = t & 1;
    if (t + 1 < NT) {
      stage(cur ^ 1, (t + 1) * 64);                     // 8 loads for t+1 in flight
      asm volatile("s_waitcnt vmcnt(8)" ::: "memory");  // tile t landed
    } else {
      asm volatile("s_waitcnt vmcnt(0)" ::: "memory");
    }
    __builtin_amdgcn_s_barrier();  // raw: no vmcnt(0) drain of prefetch
    asm volatile("" ::: "memory");

    const unsigned short* pa = lsA + cur * 16384;
    const unsigned short* pb = lsB + cur * 16384;

    KK_BLOCK(xs0)
    KK_BLOCK(xs1)

    // all ds_reads of buf[cur] retired before t+1's stage overwrites it
    asm volatile("s_waitcnt lgkmcnt(0)" ::: "memory");
    __builtin_amdgcn_sched_barrier(0);
    __builtin_amdgcn_s_barrier();
    asm volatile("" ::: "memory");
  }

  // ---- epilogue; C/D layout: col = l16 (n), row = quad*4 + r (m) ----
  const int c_base = n0 + wn * 64;                 // one GroupNorm group
  const int t_base = (m0 & (T_DIM - 1)) + wm * 128;

  LOADC(0) LOADC(1) LOADC(2) LOADC(3)

  if (c_base == 0) {  // rope on channels 0..63
#define ROPE_N8(n)                                                      \
    { int cc_ = n * 16 + l16;                                           \
      int ii_ = cc_ >> 1;                                               \
      float fr_ = expf(-(float)ii_ * 0.28782313662425572f);             \
      float sg_ = (cc_ & 1) ? 1.f : -1.f;                               \
      ROPE_M(n,0) ROPE_M(n,1) ROPE_M(n,2) ROPE_M(n,3)                   \
      ROPE_M(n,4) ROPE_M(n,5) ROPE_M(n,6) ROPE_M(n,7) }
    ROPE_N8(0) ROPE_N8(1) ROPE_N8(2) ROPE_N8(3)
  }

  GN_M(0) GN_M(1) GN_M(2) GN_M(3) GN_M(4) GN_M(5) GN_M(6) GN_M(7)

  // ---- transposed store via LDS, four 64-t chunks; waves with wm==h>>1 own chunk h ----
  const int bb = m0 >> 12;          // batch
  const int t0 = m0 & (T_DIM - 1);  // t of block row 0
#define ST1R(m,ml,n)                                                     \
  lsO[wn * 64 + n * 16 + l16][ml * 16 + quad * 4 + 0] = a##m##n[0];      \
  lsO[wn * 64 + n * 16 + l16][ml * 16 + quad * 4 + 1] = a##m##n[1];      \
  lsO[wn * 64 + n * 16 + l16][ml * 16 + quad * 4 + 2] = a##m##n[2];      \
  lsO[wn * 64 + n * 16 + l16][ml * 16 + quad * 4 + 3] = a##m##n[3];
#define ST_ROW(m,ml) ST1R(m,ml,0) ST1R(m,ml,1) ST1R(m,ml,2) ST1R(m,ml,3)
#pragma unroll
  for (int h = 0; h < 4; ++h) {
    if (wm == (h >> 1)) {
      if ((h & 1) == 0) {
        ST_ROW(0,0) ST_ROW(1,1) ST_ROW(2,2) ST_ROW(3,3)
      } else {
        ST_ROW(4,0) ST_ROW(5,1) ST_ROW(6,2) ST_ROW(7,3)
      }
    }
    __syncthreads();
    // 256 c x 64 t floats = 4096 float4 slots; 512 threads x 8
#pragma unroll
    for (int i = 0; i < 8; ++i) {
      int s = tid + i * 512;
      int cl = s >> 4;
      int t4 = (s & 15) * 4;
      float4 v = *(const float4*)&lsO[cl][t4];
      *(float4*)&out[(size_t)bb * C_DIM * T_DIM + (size_t)(n0 + cl) * T_DIM + t0 + h * 64 + t4] = v;
    }
    __syncthreads();  // before next chunk overwrites lsO
  }
}

// ======================= fp32 fallback (128^2, round-5 structure) =======================
#define FOR_MN(OP) \
  OP(0,0) OP(0,1) OP(0,2) OP(0,3) \
  OP(1,0) OP(1,1) OP(1,2) OP(1,3) \
  OP(2,0) OP(2,1) OP(2,2) OP(2,3) \
  OP(3,0) OP(3,1) OP(3,2) OP(3,3)
#define DECL_ACC(m,n) f32x4 a##m##n = {0.f, 0.f, 0.f, 0.f};

__global__ __launch_bounds__(256, 2) void gemm_fused_f32(const float* __restrict__ Av,
                                                         const unsigned short* __restrict__ Wt,
                                                         const float* __restrict__ hhb,
                                                         const float* __restrict__ gnw,
                                                         const float* __restrict__ gnb,
                                                         float* __restrict__ out) {
  __shared__ __align__(16) char smem[49152];
  float* lsAf = (float*)smem;                              // 2x4096 floats (32KB)
  unsigned short* lsB = (unsigned short*)(smem + 32768);   // 2x4096 shorts (16KB)
  float(*lsO)[68] = (float(*)[68])smem;

  const int tid = threadIdx.x;
  const int wave = tid >> 6;
  const int lane = tid & 63;
  const int quad = lane >> 4;
  const int l16 = lane & 15;
  const int wm = wave >> 1, wn = wave & 1;

  const int bid = blockIdx.x;
  const int wg = (bid & 7) * 128 + (bid >> 3);
  const int m0 = (wg >> 4) * 128;
  const int n0 = (wg & 15) * 128;

  FOR_MN(DECL_ACC)

  const int srow32 = lane >> 3;
  const int scol32 = (((lane & 7) ^ srow32) * 4);  // floats
  const int srow16 = lane >> 2;
  const int scol16 = ((lane & 3) ^ ((lane >> 3) & 3)) * 8;  // shorts
  const float* gA32 = Av + (size_t)(m0 + wave * 32 + srow32) * K_DIM + scol32;
  const unsigned short* gB16 = Wt + (size_t)(n0 + wave * 32 + srow16) * K_DIM + scol16;

  const int bxs = (quad ^ ((l16 >> 1) & 3)) * 8;
  const int bbase = (wn * 64 + l16) * 32;
  const int abasef = (wm * 64 + l16) * 32;
  const int u0 = ((2 * quad) ^ (l16 & 7)) * 4;
  const int u1 = ((2 * quad + 1) ^ (l16 & 7)) * 4;

  auto stage = [&](int d, int koff) {
    GLD16(gA32 + koff, lsAf + d * 4096 + wave * 1024);
    GLD16(gA32 + koff + 8 * K_DIM, lsAf + d * 4096 + wave * 1024 + 256);
    GLD16(gA32 + koff + 16 * K_DIM, lsAf + d * 4096 + wave * 1024 + 512);
    GLD16(gA32 + koff + 24 * K_DIM, lsAf + d * 4096 + wave * 1024 + 768);
    GLD16(gB16 + koff, lsB + d * 4096 + wave * 1024);
    GLD16(gB16 + (size_t)16 * K_DIM + koff, lsB + d * 4096 + wave * 1024 + 512);
  };

  constexpr int NT = K_DIM / 32;
  stage(0, 0);
  for (int t = 0; t < NT; ++t) {
    const int cur = t & 1;
    if (t + 1 < NT) {
      stage(cur ^ 1, (t + 1) * 32);
      asm volatile("s_waitcnt vmcnt(6)" ::: "memory");
    } else {
      asm volatile("s_waitcnt vmcnt(0)" ::: "memory");
    }
    __builtin_amdgcn_s_barrier();
    asm volatile("" ::: "memory");

    const float* paf = lsAf + cur * 4096;
    const unsigned short* pb = lsB + cur * 4096;

#define LOAD_AF32(m)                                                      \
    bf16x8 af##m;                                                         \
    { const float* ap_ = paf + abasef + m * 512;                          \
      f32x4 a0_ = *(const f32x4*)(ap_ + u0);                              \
      f32x4 a1_ = *(const f32x4*)(ap_ + u1);                              \
      af##m[0] = (__bf16)a0_[0]; af##m[1] = (__bf16)a0_[1];               \
      af##m[2] = (__bf16)a0_[2]; af##m[3] = (__bf16)a0_[3];               \
      af##m[4] = (__bf16)a1_[0]; af##m[5] = (__bf16)a1_[1];               \
      af##m[6] = (__bf16)a1_[2]; af##m[7] = (__bf16)a1_[3]; }
#define LOAD_BF32(n)                                                      \
    bf16x8 bfr##n = *(const bf16x8*)(const void*)(pb + bbase + n * 512 + bxs);

    LOAD_AF32(0) LOAD_AF32(1) LOAD_AF32(2) LOAD_AF32(3)
    LOAD_BF32(0) LOAD_BF32(1) LOAD_BF32(2) LOAD_BF32(3)
    FOR_MN(MFMA_OP)
#undef LOAD_AF32
#undef LOAD_BF32

    asm volatile("s_waitcnt lgkmcnt(0)" ::: "memory");
    __builtin_amdgcn_sched_barrier(0);
    __builtin_amdgcn_s_barrier();
    asm volatile("" ::: "memory");
  }

  const int c_base = n0 + wn * 64;
  const int t_base = (m0 & (T_DIM - 1)) + wm * 64;

  LOADC(0) LOADC(1) LOADC(2) LOADC(3)

  if (c_base == 0) {
#define ROPE_N(n)                                                       \
    { int cc_ = n * 16 + l16;                                           \
      int ii_ = cc_ >> 1;                                               \
      float fr_ = expf(-(float)ii_ * 0.28782313662425572f);             \
      float sg_ = (cc_ & 1) ? 1.f : -1.f;                                \
      ROPE_M(n,0) ROPE_M(n,1) ROPE_M(n,2) ROPE_M(n,3) }
    ROPE_N(0) ROPE_N(1) ROPE_N(2) ROPE_N(3)
  }

  GN_M(0) GN_M(1) GN_M(2) GN_M(3)

  const int bb = m0 >> 12;
  const int t0 = m0 & (T_DIM - 1);
#define ST_MN(m,n)                                                      \
  lsO[wn * 64 + n * 16 + l16][m * 16 + quad * 4 + 0] = a##m##n[0];      \
  lsO[wn * 64 + n * 16 + l16][m * 16 + quad * 4 + 1] = a##m##n[1];      \
  lsO[wn * 64 + n * 16 + l16][m * 16 + quad * 4 + 2] = a##m##n[2];      \
  lsO[wn * 64 + n * 16 + l16][m * 16 + quad * 4 + 3] = a##m##n[3];
#pragma unroll
  for (int h = 0; h < 2; ++h) {
    if (wm == h) {
      FOR_MN(ST_MN)
    }
    __syncthreads();
#pragma unroll
    for (int i = 0; i < 8; ++i) {
      int s = tid + i * 256;
      int cl = s >> 4;
      int t4 = (s & 15) * 4;
      float4 v = *(const float4*)&lsO[cl][t4];
      *(float4*)&out[(size_t)bb * C_DIM * T_DIM + (size_t)(n0 + cl) * T_DIM + t0 + h * 64 + t4] = v;
    }
    __syncthreads();
  }
}

// ---------------- S_n passthrough: (2,2048) fp32 after the big tensor ----------------
__global__ __launch_bounds__(256) void copy_sn(const float* __restrict__ src,
                                               float* __restrict__ dst) {
  int i = blockIdx.x * 256 + threadIdx.x;  // 0..4095
  dst[i] = src[i];
}

extern "C" void kernel_launch(void* const* d_in, const int* in_sizes, int n_in,
                              void* d_out, int out_size, void* d_ws, size_t ws_size,
                              hipStream_t stream) {
  const float* X = (const float*)d_in[0];
  const float* Sn = (const float*)d_in[1];
  const float* W = (const float*)d_in[2];
  const float* hhb = (const float*)d_in[3];
  const float* gnw = (const float*)d_in[4];
  const float* gnb = (const float*)d_in[5];
  float* out = (float*)d_out;

  // workspace layout: Wt bf16 [2048][2048] = 8 MB (always);
  // optional Xb bf16 [8192][2048] = 33.5 MB iff workspace is big enough.
  unsigned short* Wt = (unsigned short*)d_ws;
  const size_t wt_bytes = (size_t)C_DIM * K_DIM * 2;      // 8 MB
  const size_t xb_bytes = (size_t)2 * T_DIM * K_DIM * 2;  // 33.5 MB

  transpose_w<<<dim3(32, 32), dim3(256), 0, stream>>>(W, Wt);

  if (ws_size >= wt_bytes + xb_bytes) {
    unsigned short* Xb = Wt + (size_t)C_DIM * K_DIM;
    cvt_x<<<dim3(8192), dim3(256), 0, stream>>>(X, Xb);
    gemm_fused256<<<dim3(256), dim3(512), 0, stream>>>(Xb, Wt, hhb, gnw, gnb, out);
  } else {
    gemm_fused_f32<<<dim3(1024), dim3(256), 0, stream>>>(X, Wt, hhb, gnw, gnb, out);
  }

  copy_sn<<<dim3(16), dim3(256), 0, stream>>>(Sn, out + (size_t)16777216);
}

// Round 9
// 434.503 us; speedup vs baseline: 1.0018x; 1.0018x over previous
//
#include <hip/hip_runtime.h>

#define T_DIM 4096
#define C_DIM 2048
#define K_DIM 2048

typedef __bf16 bf16x8 __attribute__((ext_vector_type(8)));
typedef float f32x4 __attribute__((ext_vector_type(4)));

__device__ __forceinline__ unsigned short f2bf(float f) {
  union { float f; unsigned int i; } x;
  x.f = f;
  unsigned int r = x.i + 0x7fffu + ((x.i >> 16) & 1u);  // round-to-nearest-even
  return (unsigned short)(r >> 16);
}

// async global->LDS, 16B per lane; LDS dest = wave-uniform base + lane*16
#define GLD16(gsrc, ldst)                                                   \
  __builtin_amdgcn_global_load_lds(                                         \
      (const __attribute__((address_space(1))) unsigned int*)(gsrc),        \
      (__attribute__((address_space(3))) unsigned int*)(ldst), 16, 0, 0)

// ---------------- W (K x N) fp32 -> Wt (N x K) bf16 ----------------
__global__ __launch_bounds__(256) void transpose_w(const float* __restrict__ W,
                                                   unsigned short* __restrict__ Wt) {
  __shared__ float tile[64][68];  // +4 pad
  const int c0 = blockIdx.x * 64;  // n
  const int r0 = blockIdx.y * 64;  // k
  const int tid = threadIdx.x;
#pragma unroll
  for (int i = 0; i < 4; ++i) {
    int s = tid + i * 256;  // 0..1023 float4 slots (64 rows x 16 slots)
    int r = s >> 4, c4 = (s & 15) * 4;
    *(float4*)&tile[r][c4] = *(const float4*)&W[(size_t)(r0 + r) * C_DIM + c0 + c4];
  }
  __syncthreads();
#pragma unroll
  for (int i = 0; i < 2; ++i) {
    int s = tid + i * 256;  // 0..511: 64 n-rows x 8 slots of 8 bf16
    int n = s >> 3, k8 = (s & 7) * 8;
    __align__(16) unsigned short tmp[8];
#pragma unroll
    for (int j = 0; j < 8; ++j) tmp[j] = f2bf(tile[k8 + j][n]);
    *(uint4*)&Wt[(size_t)(c0 + n) * K_DIM + r0 + k8] = *(uint4*)tmp;
  }
}

// ---------------- X fp32 -> Xb bf16 (one pass, RNE identical to f2bf staging) ----------------
__global__ __launch_bounds__(256) void cvt_x(const float* __restrict__ X,
                                             unsigned short* __restrict__ Xb) {
  size_t base = (size_t)blockIdx.x * 2048 + (size_t)threadIdx.x * 8;
  float4 a = *(const float4*)&X[base];
  float4 b = *(const float4*)&X[base + 4];
  __align__(16) unsigned short t[8];
  t[0] = f2bf(a.x); t[1] = f2bf(a.y); t[2] = f2bf(a.z); t[3] = f2bf(a.w);
  t[4] = f2bf(b.x); t[5] = f2bf(b.y); t[6] = f2bf(b.z); t[7] = f2bf(b.w);
  *(uint4*)&Xb[base] = *(const uint4*)t;
}

// -------- shared epilogue macros (reference locals of the enclosing kernel) --------
#define MFMA_OP(m,n) \
  a##m##n = __builtin_amdgcn_mfma_f32_16x16x32_bf16(af##m, bfr##n, a##m##n, 0, 0, 0);

#define LOADC(n)                                  \
  const int c##n = c_base + n * 16 + l16;         \
  const float hb##n = hhb[c##n];                  \
  const float gw##n = gnw[c##n];                  \
  const float gb##n = gnb[c##n];

#define ROPE_E(n,m,r)                                                   \
    { float v_ = a##m##n[r];                                            \
      float p_ = __shfl_xor(v_, 1, 64);                                 \
      int t_ = t_base + m * 16 + quad * 4 + r;                          \
      float ang_ = (float)t_ * fr_;                                     \
      float s_ = sinf(ang_);                                            \
      float co_ = cosf(ang_);                                           \
      a##m##n[r] = v_ * co_ + sg_ * p_ * s_; }
#define ROPE_M(n,m) ROPE_E(n,m,0) ROPE_E(n,m,1) ROPE_E(n,m,2) ROPE_E(n,m,3)

#define GN_ROW(m,r)                                                     \
  { float h0_ = tanhf(fmaxf(a##m##0[r], 0.f) + hb0);                    \
    float h1_ = tanhf(fmaxf(a##m##1[r], 0.f) + hb1);                    \
    float h2_ = tanhf(fmaxf(a##m##2[r], 0.f) + hb2);                    \
    float h3_ = tanhf(fmaxf(a##m##3[r], 0.f) + hb3);                    \
    float s1_ = h0_ + h1_ + h2_ + h3_;                                  \
    float s2_ = h0_ * h0_ + h1_ * h1_ + h2_ * h2_ + h3_ * h3_;          \
    s1_ += __shfl_xor(s1_, 1, 64);  s2_ += __shfl_xor(s2_, 1, 64);      \
    s1_ += __shfl_xor(s1_, 2, 64);  s2_ += __shfl_xor(s2_, 2, 64);      \
    s1_ += __shfl_xor(s1_, 4, 64);  s2_ += __shfl_xor(s2_, 4, 64);      \
    s1_ += __shfl_xor(s1_, 8, 64);  s2_ += __shfl_xor(s2_, 8, 64);      \
    float mu_ = s1_ * 0.015625f;                                        \
    float var_ = s2_ * 0.015625f - mu_ * mu_;                           \
    float rs_ = rsqrtf(var_ + 1e-5f);                                   \
    a##m##0[r] = (h0_ - mu_) * rs_ * gw0 + gb0;                         \
    a##m##1[r] = (h1_ - mu_) * rs_ * gw1 + gb1;                         \
    a##m##2[r] = (h2_ - mu_) * rs_ * gw2 + gb2;                         \
    a##m##3[r] = (h3_ - mu_) * rs_ * gw3 + gb3; }
#define GN_M(m) GN_ROW(m,0) GN_ROW(m,1) GN_ROW(m,2) GN_ROW(m,3)

// ======================= 256x256-tile bf16 fast path =======================
// 512 threads (8 waves: wm=wave>>2, wn=wave&3). Per wave: 128m x 64n (32 f32x4
// acc = 128 AGPR). 2 waves/SIMD -> hard 256-unified-reg/wave cap. K-step is
// ordered as B-PAIRS with sched_barrier(0) fences so the pre-RA scheduler
// cannot hoist: peak frag live = 8(B-pair) + 32(A) = 40 regs. (Rounds 7/8:
// unconstrained scheduler kept 48+ live -> ~30-reg scratch spill, +107MB
// WRITE. C-level scoping was a no-op: identical counters.) BK=64 dbuf (128KB
// LDS), counted vmcnt(8), raw barriers, bank-perfect XOR swizzle (row&7).
#define FOR_MN8(OP) \
  OP(0,0) OP(0,1) OP(0,2) OP(0,3) OP(1,0) OP(1,1) OP(1,2) OP(1,3) \
  OP(2,0) OP(2,1) OP(2,2) OP(2,3) OP(3,0) OP(3,1) OP(3,2) OP(3,3) \
  OP(4,0) OP(4,1) OP(4,2) OP(4,3) OP(5,0) OP(5,1) OP(5,2) OP(5,3) \
  OP(6,0) OP(6,1) OP(6,2) OP(6,3) OP(7,0) OP(7,1) OP(7,2) OP(7,3)
#define DECL_ACC8(m,n) f32x4 a##m##n = {0.f, 0.f, 0.f, 0.f};

#define LDS_LD(p) (*(const bf16x8*)(const void*)(p))
#define MFMA1(ar, f, bn) \
  a##ar##bn = __builtin_amdgcn_mfma_f32_16x16x32_bf16(f, b##bn, a##ar##bn, 0, 0, 0);

// one kk half (K=32): A loaded ONCE (32 regs, live across both halves);
// B in 2 pairs of 8 regs; sched_barrier(0) pins the split (peak 40 frag regs).
#define KK_BLOCK(XS)                                                        \
  {                                                                         \
    bf16x8 b0 = LDS_LD(pb + bbase + 0 * 1024 + (XS));                       \
    bf16x8 b1 = LDS_LD(pb + bbase + 1 * 1024 + (XS));                       \
    bf16x8 f0 = LDS_LD(pa + abase + 0 * 1024 + (XS));                       \
    bf16x8 f1 = LDS_LD(pa + abase + 1 * 1024 + (XS));                       \
    bf16x8 f2 = LDS_LD(pa + abase + 2 * 1024 + (XS));                       \
    bf16x8 f3 = LDS_LD(pa + abase + 3 * 1024 + (XS));                       \
    bf16x8 f4 = LDS_LD(pa + abase + 4 * 1024 + (XS));                       \
    bf16x8 f5 = LDS_LD(pa + abase + 5 * 1024 + (XS));                       \
    bf16x8 f6 = LDS_LD(pa + abase + 6 * 1024 + (XS));                       \
    bf16x8 f7 = LDS_LD(pa + abase + 7 * 1024 + (XS));                       \
    MFMA1(0, f0, 0) MFMA1(0, f0, 1) MFMA1(1, f1, 0) MFMA1(1, f1, 1)         \
    MFMA1(2, f2, 0) MFMA1(2, f2, 1) MFMA1(3, f3, 0) MFMA1(3, f3, 1)         \
    MFMA1(4, f4, 0) MFMA1(4, f4, 1) MFMA1(5, f5, 0) MFMA1(5, f5, 1)         \
    MFMA1(6, f6, 0) MFMA1(6, f6, 1) MFMA1(7, f7, 0) MFMA1(7, f7, 1)         \
    __builtin_amdgcn_sched_barrier(0);                                      \
    bf16x8 b2 = LDS_LD(pb + bbase + 2 * 1024 + (XS));                       \
    bf16x8 b3 = LDS_LD(pb + bbase + 3 * 1024 + (XS));                       \
    MFMA1(0, f0, 2) MFMA1(0, f0, 3) MFMA1(1, f1, 2) MFMA1(1, f1, 3)         \
    MFMA1(2, f2, 2) MFMA1(2, f2, 3) MFMA1(3, f3, 2) MFMA1(3, f3, 3)         \
    MFMA1(4, f4, 2) MFMA1(4, f4, 3) MFMA1(5, f5, 2) MFMA1(5, f5, 3)         \
    MFMA1(6, f6, 2) MFMA1(6, f6, 3) MFMA1(7, f7, 2) MFMA1(7, f7, 3)         \
    __builtin_amdgcn_sched_barrier(0);                                      \
  }

__global__ __launch_bounds__(512, 2) void gemm_fused256(const unsigned short* __restrict__ Xb,
                                                        const unsigned short* __restrict__ Wt,
                                                        const float* __restrict__ hhb,
                                                        const float* __restrict__ gnw,
                                                        const float* __restrict__ gnb,
                                                        float* __restrict__ out) {
  __shared__ __align__(16) char smem[131072];             // 2x32KB A + 2x32KB B
  unsigned short* lsA = (unsigned short*)smem;            // [2][256][64] bf16
  unsigned short* lsB = (unsigned short*)(smem + 65536);  // [2][256][64] bf16
  float(*lsO)[68] = (float(*)[68])smem;                   // epilogue: [256][68] f32, 69.6KB

  const int tid = threadIdx.x;
  const int wave = tid >> 6;   // 0..7
  const int lane = tid & 63;
  const int quad = lane >> 4;
  const int l16 = lane & 15;
  const int wm = wave >> 2, wn = wave & 3;

  // XCD-aware: 256 blocks, XCD = bid&7 owns one n-column (B panel L2-resident)
  const int bid = blockIdx.x;
  const int wg = (bid & 7) * 32 + (bid >> 3);
  const int n0 = (wg >> 5) * 256;  // 8 n-blocks
  const int m0 = (wg & 31) * 256;  // 32 m-blocks

  FOR_MN8(DECL_ACC8)

  // staging: tile [256][64] shorts (128B rows); GLD16 covers 8 rows; wave w owns
  // rows [w*32, w*32+32) via 4 issues. lane -> row lane>>3, unit (lane&7)^(row&7).
  const int srow = lane >> 3;
  const int scol = ((lane & 7) ^ (srow & 7)) * 8;  // shorts
  const unsigned short* gA = Xb + (size_t)(m0 + wave * 32 + srow) * K_DIM + scol;
  const unsigned short* gB = Wt + (size_t)(n0 + wave * 32 + srow) * K_DIM + scol;

  // fragment reads: A row = wm*128 + mf*16 + l16, B row = wn*64 + nf*16 + l16;
  // row&7 == l16&7 -> xs = (kk*32 + quad*8) ^ ((l16&7)<<3)
  const int xs0 = (quad * 8) ^ ((l16 & 7) << 3);
  const int xs1 = (32 + quad * 8) ^ ((l16 & 7) << 3);
  const int abase = (wm * 128 + l16) * 64;  // + mf*1024 + xs
  const int bbase = (wn * 64 + l16) * 64;   // + nf*1024 + xs

  auto stage = [&](int d, int koff) {
#pragma unroll
    for (int r = 0; r < 4; ++r)
      GLD16(gA + (size_t)(r * 8) * K_DIM + koff, lsA + d * 16384 + wave * 2048 + r * 512);
#pragma unroll
    for (int r = 0; r < 4; ++r)
      GLD16(gB + (size_t)(r * 8) * K_DIM + koff, lsB + d * 16384 + wave * 2048 + r * 512);
  };

  constexpr int NT = K_DIM / 64;  // 32 K-tiles
  stage(0, 0);                    // prologue: tile 0 in flight
  for (int t = 0; t < NT; ++t) {
    const int cur = t & 1;
    if (t + 1 < NT) {
      stage(cur ^ 1, (t + 1) * 64);                     // 8 loads for t+1 in flight
      asm volatile("s_waitcnt vmcnt(8)" ::: "memory");  // tile t landed
    } else {
      asm volatile("s_waitcnt vmcnt(0)" ::: "memory");
    }
    __builtin_amdgcn_s_barrier();  // raw: no vmcnt(0) drain of prefetch
    asm volatile("" ::: "memory");

    const unsigned short* pa = lsA + cur * 16384;
    const unsigned short* pb = lsB + cur * 16384;

    KK_BLOCK(xs0)
    KK_BLOCK(xs1)

    // all ds_reads of buf[cur] retired before t+1's stage overwrites it
    asm volatile("s_waitcnt lgkmcnt(0)" ::: "memory");
    __builtin_amdgcn_sched_barrier(0);
    __builtin_amdgcn_s_barrier();
    asm volatile("" ::: "memory");
  }

  // ---- epilogue; C/D layout: col = l16 (n), row = quad*4 + r (m) ----
  const int c_base = n0 + wn * 64;                 // one GroupNorm group
  const int t_base = (m0 & (T_DIM - 1)) + wm * 128;

  LOADC(0) LOADC(1) LOADC(2) LOADC(3)

  if (c_base == 0) {  // rope on channels 0..63
#define ROPE_N8(n)                                                      \
    { int cc_ = n * 16 + l16;                                           \
      int ii_ = cc_ >> 1;                                               \
      float fr_ = expf(-(float)ii_ * 0.28782313662425572f);             \
      float sg_ = (cc_ & 1) ? 1.f : -1.f;                               \
      ROPE_M(n,0) ROPE_M(n,1) ROPE_M(n,2) ROPE_M(n,3)                   \
      ROPE_M(n,4) ROPE_M(n,5) ROPE_M(n,6) ROPE_M(n,7) }
    ROPE_N8(0) ROPE_N8(1) ROPE_N8(2) ROPE_N8(3)
  }

  GN_M(0) GN_M(1) GN_M(2) GN_M(3) GN_M(4) GN_M(5) GN_M(6) GN_M(7)

  // ---- transposed store via LDS, four 64-t chunks; waves with wm==h>>1 own chunk h ----
  const int bb = m0 >> 12;          // batch
  const int t0 = m0 & (T_DIM - 1);  // t of block row 0
#define ST1R(m,ml,n)                                                     \
  lsO[wn * 64 + n * 16 + l16][ml * 16 + quad * 4 + 0] = a##m##n[0];      \
  lsO[wn * 64 + n * 16 + l16][ml * 16 + quad * 4 + 1] = a##m##n[1];      \
  lsO[wn * 64 + n * 16 + l16][ml * 16 + quad * 4 + 2] = a##m##n[2];      \
  lsO[wn * 64 + n * 16 + l16][ml * 16 + quad * 4 + 3] = a##m##n[3];
#define ST_ROW(m,ml) ST1R(m,ml,0) ST1R(m,ml,1) ST1R(m,ml,2) ST1R(m,ml,3)
#pragma unroll
  for (int h = 0; h < 4; ++h) {
    if (wm == (h >> 1)) {
      if ((h & 1) == 0) {
        ST_ROW(0,0) ST_ROW(1,1) ST_ROW(2,2) ST_ROW(3,3)
      } else {
        ST_ROW(4,0) ST_ROW(5,1) ST_ROW(6,2) ST_ROW(7,3)
      }
    }
    __syncthreads();
    // 256 c x 64 t floats = 4096 float4 slots; 512 threads x 8
#pragma unroll
    for (int i = 0; i < 8; ++i) {
      int s = tid + i * 512;
      int cl = s >> 4;
      int t4 = (s & 15) * 4;
      float4 v = *(const float4*)&lsO[cl][t4];
      *(float4*)&out[(size_t)bb * C_DIM * T_DIM + (size_t)(n0 + cl) * T_DIM + t0 + h * 64 + t4] = v;
    }
    __syncthreads();  // before next chunk overwrites lsO
  }
}

// ======================= fp32 fallback (128^2, round-5 structure) =======================
#define FOR_MN(OP) \
  OP(0,0) OP(0,1) OP(0,2) OP(0,3) \
  OP(1,0) OP(1,1) OP(1,2) OP(1,3) \
  OP(2,0) OP(2,1) OP(2,2) OP(2,3) \
  OP(3,0) OP(3,1) OP(3,2) OP(3,3)
#define DECL_ACC(m,n) f32x4 a##m##n = {0.f, 0.f, 0.f, 0.f};

__global__ __launch_bounds__(256, 2) void gemm_fused_f32(const float* __restrict__ Av,
                                                         const unsigned short* __restrict__ Wt,
                                                         const float* __restrict__ hhb,
                                                         const float* __restrict__ gnw,
                                                         const float* __restrict__ gnb,
                                                         float* __restrict__ out) {
  __shared__ __align__(16) char smem[49152];
  float* lsAf = (float*)smem;                              // 2x4096 floats (32KB)
  unsigned short* lsB = (unsigned short*)(smem + 32768);   // 2x4096 shorts (16KB)
  float(*lsO)[68] = (float(*)[68])smem;

  const int tid = threadIdx.x;
  const int wave = tid >> 6;
  const int lane = tid & 63;
  const int quad = lane >> 4;
  const int l16 = lane & 15;
  const int wm = wave >> 1, wn = wave & 1;

  const int bid = blockIdx.x;
  const int wg = (bid & 7) * 128 + (bid >> 3);
  const int m0 = (wg >> 4) * 128;
  const int n0 = (wg & 15) * 128;

  FOR_MN(DECL_ACC)

  const int srow32 = lane >> 3;
  const int scol32 = (((lane & 7) ^ srow32) * 4);  // floats
  const int srow16 = lane >> 2;
  const int scol16 = ((lane & 3) ^ ((lane >> 3) & 3)) * 8;  // shorts
  const float* gA32 = Av + (size_t)(m0 + wave * 32 + srow32) * K_DIM + scol32;
  const unsigned short* gB16 = Wt + (size_t)(n0 + wave * 32 + srow16) * K_DIM + scol16;

  const int bxs = (quad ^ ((l16 >> 1) & 3)) * 8;
  const int bbase = (wn * 64 + l16) * 32;
  const int abasef = (wm * 64 + l16) * 32;
  const int u0 = ((2 * quad) ^ (l16 & 7)) * 4;
  const int u1 = ((2 * quad + 1) ^ (l16 & 7)) * 4;

  auto stage = [&](int d, int koff) {
    GLD16(gA32 + koff, lsAf + d * 4096 + wave * 1024);
    GLD16(gA32 + koff + 8 * K_DIM, lsAf + d * 4096 + wave * 1024 + 256);
    GLD16(gA32 + koff + 16 * K_DIM, lsAf + d * 4096 + wave * 1024 + 512);
    GLD16(gA32 + koff + 24 * K_DIM, lsAf + d * 4096 + wave * 1024 + 768);
    GLD16(gB16 + koff, lsB + d * 4096 + wave * 1024);
    GLD16(gB16 + (size_t)16 * K_DIM + koff, lsB + d * 4096 + wave * 1024 + 512);
  };

  constexpr int NT = K_DIM / 32;
  stage(0, 0);
  for (int t = 0; t < NT; ++t) {
    const int cur = t & 1;
    if (t + 1 < NT) {
      stage(cur ^ 1, (t + 1) * 32);
      asm volatile("s_waitcnt vmcnt(6)" ::: "memory");
    } else {
      asm volatile("s_waitcnt vmcnt(0)" ::: "memory");
    }
    __builtin_amdgcn_s_barrier();
    asm volatile("" ::: "memory");

    const float* paf = lsAf + cur * 4096;
    const unsigned short* pb = lsB + cur * 4096;

#define LOAD_AF32(m)                                                      \
    bf16x8 af##m;                                                         \
    { const float* ap_ = paf + abasef + m * 512;                          \
      f32x4 a0_ = *(const f32x4*)(ap_ + u0);                              \
      f32x4 a1_ = *(const f32x4*)(ap_ + u1);                              \
      af##m[0] = (__bf16)a0_[0]; af##m[1] = (__bf16)a0_[1];               \
      af##m[2] = (__bf16)a0_[2]; af##m[3] = (__bf16)a0_[3];               \
      af##m[4] = (__bf16)a1_[0]; af##m[5] = (__bf16)a1_[1];               \
      af##m[6] = (__bf16)a1_[2]; af##m[7] = (__bf16)a1_[3]; }
#define LOAD_BF32(n)                                                      \
    bf16x8 bfr##n = *(const bf16x8*)(const void*)(pb + bbase + n * 512 + bxs);

    LOAD_AF32(0) LOAD_AF32(1) LOAD_AF32(2) LOAD_AF32(3)
    LOAD_BF32(0) LOAD_BF32(1) LOAD_BF32(2) LOAD_BF32(3)
    FOR_MN(MFMA_OP)
#undef LOAD_AF32
#undef LOAD_BF32

    asm volatile("s_waitcnt lgkmcnt(0)" ::: "memory");
    __builtin_amdgcn_sched_barrier(0);
    __builtin_amdgcn_s_barrier();
    asm volatile("" ::: "memory");
  }

  const int c_base = n0 + wn * 64;
  const int t_base = (m0 & (T_DIM - 1)) + wm * 64;

  LOADC(0) LOADC(1) LOADC(2) LOADC(3)

  if (c_base == 0) {
#define ROPE_N(n)                                                       \
    { int cc_ = n * 16 + l16;                                           \
      int ii_ = cc_ >> 1;                                               \
      float fr_ = expf(-(float)ii_ * 0.28782313662425572f);             \
      float sg_ = (cc_ & 1) ? 1.f : -1.f;                                \
      ROPE_M(n,0) ROPE_M(n,1) ROPE_M(n,2) ROPE_M(n,3) }
    ROPE_N(0) ROPE_N(1) ROPE_N(2) ROPE_N(3)
  }

  GN_M(0) GN_M(1) GN_M(2) GN_M(3)

  const int bb = m0 >> 12;
  const int t0 = m0 & (T_DIM - 1);
#define ST_MN(m,n)                                                      \
  lsO[wn * 64 + n * 16 + l16][m * 16 + quad * 4 + 0] = a##m##n[0];      \
  lsO[wn * 64 + n * 16 + l16][m * 16 + quad * 4 + 1] = a##m##n[1];      \
  lsO[wn * 64 + n * 16 + l16][m * 16 + quad * 4 + 2] = a##m##n[2];      \
  lsO[wn * 64 + n * 16 + l16][m * 16 + quad * 4 + 3] = a##m##n[3];
#pragma unroll
  for (int h = 0; h < 2; ++h) {
    if (wm == h) {
      FOR_MN(ST_MN)
    }
    __syncthreads();
#pragma unroll
    for (int i = 0; i < 8; ++i) {
      int s = tid + i * 256;
      int cl = s >> 4;
      int t4 = (s & 15) * 4;
      float4 v = *(const float4*)&lsO[cl][t4];
      *(float4*)&out[(size_t)bb * C_DIM * T_DIM + (size_t)(n0 + cl) * T_DIM + t0 + h * 64 + t4] = v;
    }
    __syncthreads();
  }
}

// ---------------- S_n passthrough: (2,2048) fp32 after the big tensor ----------------
__global__ __launch_bounds__(256) void copy_sn(const float* __restrict__ src,
                                               float* __restrict__ dst) {
  int i = blockIdx.x * 256 + threadIdx.x;  // 0..4095
  dst[i] = src[i];
}

extern "C" void kernel_launch(void* const* d_in, const int* in_sizes, int n_in,
                              void* d_out, int out_size, void* d_ws, size_t ws_size,
                              hipStream_t stream) {
  const float* X = (const float*)d_in[0];
  const float* Sn = (const float*)d_in[1];
  const float* W = (const float*)d_in[2];
  const float* hhb = (const float*)d_in[3];
  const float* gnw = (const float*)d_in[4];
  const float* gnb = (const float*)d_in[5];
  float* out = (float*)d_out;

  // workspace layout: Wt bf16 [2048][2048] = 8 MB (always);
  // optional Xb bf16 [8192][2048] = 33.5 MB iff workspace is big enough.
  unsigned short* Wt = (unsigned short*)d_ws;
  const size_t wt_bytes = (size_t)C_DIM * K_DIM * 2;      // 8 MB
  const size_t xb_bytes = (size_t)2 * T_DIM * K_DIM * 2;  // 33.5 MB

  transpose_w<<<dim3(32, 32), dim3(256), 0, stream>>>(W, Wt);

  if (ws_size >= wt_bytes + xb_bytes) {
    unsigned short* Xb = Wt + (size_t)C_DIM * K_DIM;
    cvt_x<<<dim3(8192), dim3(256), 0, stream>>>(X, Xb);
    gemm_fused256<<<dim3(256), dim3(512), 0, stream>>>(Xb, Wt, hhb, gnw, gnb, out);
  } else {
    gemm_fused_f32<<<dim3(1024), dim3(256), 0, stream>>>(X, Wt, hhb, gnw, gnb, out);
  }

  copy_sn<<<dim3(16), dim3(256), 0, stream>>>(Sn, out + (size_t)16777216);
}

// Round 10
// 341.872 us; speedup vs baseline: 1.2732x; 1.2710x over previous
//
#include <hip/hip_runtime.h>

#define T_DIM 4096
#define C_DIM 2048
#define K_DIM 2048

typedef __bf16 bf16x8 __attribute__((ext_vector_type(8)));
typedef float f32x4 __attribute__((ext_vector_type(4)));

__device__ __forceinline__ unsigned short f2bf(float f) {
  union { float f; unsigned int i; } x;
  x.f = f;
  unsigned int r = x.i + 0x7fffu + ((x.i >> 16) & 1u);  // round-to-nearest-even
  return (unsigned short)(r >> 16);
}

// async global->LDS, 16B per lane; LDS dest = wave-uniform base + lane*16
#define GLD16(gsrc, ldst)                                                   \
  __builtin_amdgcn_global_load_lds(                                         \
      (const __attribute__((address_space(1))) unsigned int*)(gsrc),        \
      (__attribute__((address_space(3))) unsigned int*)(ldst), 16, 0, 0)

// ---------------- W (K x N) fp32 -> Wt (N x K) bf16 ----------------
__global__ __launch_bounds__(256) void transpose_w(const float* __restrict__ W,
                                                   unsigned short* __restrict__ Wt) {
  __shared__ float tile[64][68];  // +4 pad
  const int c0 = blockIdx.x * 64;  // n
  const int r0 = blockIdx.y * 64;  // k
  const int tid = threadIdx.x;
#pragma unroll
  for (int i = 0; i < 4; ++i) {
    int s = tid + i * 256;  // 0..1023 float4 slots (64 rows x 16 slots)
    int r = s >> 4, c4 = (s & 15) * 4;
    *(float4*)&tile[r][c4] = *(const float4*)&W[(size_t)(r0 + r) * C_DIM + c0 + c4];
  }
  __syncthreads();
#pragma unroll
  for (int i = 0; i < 2; ++i) {
    int s = tid + i * 256;  // 0..511: 64 n-rows x 8 slots of 8 bf16
    int n = s >> 3, k8 = (s & 7) * 8;
    __align__(16) unsigned short tmp[8];
#pragma unroll
    for (int j = 0; j < 8; ++j) tmp[j] = f2bf(tile[k8 + j][n]);
    *(uint4*)&Wt[(size_t)(c0 + n) * K_DIM + r0 + k8] = *(uint4*)tmp;
  }
}

// ---------------- X fp32 -> Xb bf16 (one pass, RNE identical to f2bf staging) ----------------
__global__ __launch_bounds__(256) void cvt_x(const float* __restrict__ X,
                                             unsigned short* __restrict__ Xb) {
  size_t base = (size_t)blockIdx.x * 2048 + (size_t)threadIdx.x * 8;
  float4 a = *(const float4*)&X[base];
  float4 b = *(const float4*)&X[base + 4];
  __align__(16) unsigned short t[8];
  t[0] = f2bf(a.x); t[1] = f2bf(a.y); t[2] = f2bf(a.z); t[3] = f2bf(a.w);
  t[4] = f2bf(b.x); t[5] = f2bf(b.y); t[6] = f2bf(b.z); t[7] = f2bf(b.w);
  *(uint4*)&Xb[base] = *(const uint4*)t;
}

// -------- macro helpers: named accumulators (forces SROA -> registers) --------
#define FOR_MN(OP) \
  OP(0,0) OP(0,1) OP(0,2) OP(0,3) \
  OP(1,0) OP(1,1) OP(1,2) OP(1,3) \
  OP(2,0) OP(2,1) OP(2,2) OP(2,3) \
  OP(3,0) OP(3,1) OP(3,2) OP(3,3)

#define DECL_ACC(m,n) f32x4 a##m##n = {0.f, 0.f, 0.f, 0.f};

#define MFMA_OP(m,n) \
  a##m##n = __builtin_amdgcn_mfma_f32_16x16x32_bf16(af##m, bfr##n, a##m##n, 0, 0, 0);

// ------- fused GEMM + rope + relu + bias + tanh + GroupNorm + transpose -------
// Round-5 proven substrate (176us gemm, WRITE clean 72768KB, no spill):
// bf16 path BK=64 dbuf (64KB LDS, 2 blocks/CU), counted vmcnt(8) + raw
// barriers, bank-perfect XOR swizzle (row&7) on staging source and ds_read.
// ONLY change this round: block->tile mapping. Old mapping gave each XCD
// 8m x 16n panels = 12MB working set on 4MB L2 -> thrash (staging ran at
// 6.1 TB/s vs m97's 13.2 TB/s same-structure reference). New mapping: each
// XCD owns 2 n-panels (B = 1MB, L2-resident) and sweeps m with block pairs
// (i&1 = n-toggle) sharing each A-panel -> L3-side traffic ~1GB -> ~280MB.
template <bool ABF16>
__global__ __launch_bounds__(256, 2) void gemm_fused(const void* __restrict__ Av,
                                                     const unsigned short* __restrict__ Wt,
                                                     const float* __restrict__ hhb,
                                                     const float* __restrict__ gnw,
                                                     const float* __restrict__ gnb,
                                                     float* __restrict__ out) {
  // bf16: A bufs 2x8192 shorts @0 (32KB), B bufs 2x8192 shorts @32768 (32KB).
  // fp32: Af bufs 2x4096 floats @0 (32KB), B bufs 2x4096 shorts @32768 (16KB).
  constexpr int SMEM_BYTES = ABF16 ? 65536 : 49152;
  __shared__ __align__(16) char smem[SMEM_BYTES];
  unsigned short* lsA = (unsigned short*)smem;
  float* lsAf = (float*)smem;
  unsigned short* lsB = (unsigned short*)(smem + 32768);
  float(*lsO)[68] = (float(*)[68])smem;  // epilogue reuse (34.8KB <= SMEM)

  const int tid = threadIdx.x;
  const int wave = tid >> 6;
  const int lane = tid & 63;
  const int quad = lane >> 4;
  const int l16 = lane & 15;
  const int wm = wave >> 1, wn = wave & 1;

  // L2-locality mapping: xcd = bid&7 owns n-panels {2*xcd, 2*xcd+1};
  // i>>1 sweeps m (paired blocks i=2j,2j+1 share the A-panel).
  const int xcd = blockIdx.x & 7;
  const int i = blockIdx.x >> 3;             // 0..127 within XCD
  const int n0 = (xcd * 2 + (i & 1)) * 128;  // B panel stays L2-resident (1MB/XCD)
  const int m0 = (i >> 1) * 128;             // 64 m-panels streamed

  FOR_MN(DECL_ACC)

  if constexpr (ABF16) {
    // ---- BK=64 staging: tile [128][64] shorts (128B rows); GLD16 covers 8 rows.
    //   lane -> row lane>>3, col8 = lane&7; source col8 ^= (row&7)  (involution)
    const int srow = lane >> 3;
    const int scol = ((lane & 7) ^ (srow & 7)) * 8;
    const unsigned short* gA =
        (const unsigned short*)Av + (size_t)(m0 + wave * 32 + srow) * K_DIM + scol;
    const unsigned short* gB =
        Wt + (size_t)(n0 + wave * 32 + srow) * K_DIM + scol;

    // fragment reads: row R = (wm|wn)*64 + m*16 + l16 (R&7 == l16&7), col kk*32+quad*8
    const int xs0 = (quad * 8) ^ ((l16 & 7) << 3);
    const int xs1 = (32 + quad * 8) ^ ((l16 & 7) << 3);
    const int abase = (wm * 64 + l16) * 64;  // shorts; + m*1024 + xs
    const int bbase = (wn * 64 + l16) * 64;  // shorts; + n*1024 + xs

    auto stage = [&](int d, int koff) {
#pragma unroll
      for (int r = 0; r < 4; ++r)
        GLD16(gA + (size_t)(r * 8) * K_DIM + koff, lsA + d * 8192 + wave * 2048 + r * 512);
#pragma unroll
      for (int r = 0; r < 4; ++r)
        GLD16(gB + (size_t)(r * 8) * K_DIM + koff, lsB + d * 8192 + wave * 2048 + r * 512);
    };

    constexpr int NT = K_DIM / 64;  // 32 K-tiles
    stage(0, 0);                    // prologue: tile 0 in flight
    for (int t = 0; t < NT; ++t) {
      const int cur = t & 1;
      if (t + 1 < NT) {
        stage(cur ^ 1, (t + 1) * 64);  // 8 loads for t+1 stay in flight
        asm volatile("s_waitcnt vmcnt(8)" ::: "memory");  // tile t landed
      } else {
        asm volatile("s_waitcnt vmcnt(0)" ::: "memory");
      }
      __builtin_amdgcn_s_barrier();  // raw: no vmcnt(0) drain of prefetch
      asm volatile("" ::: "memory");

      const unsigned short* pa = lsA + cur * 8192;
      const unsigned short* pb = lsB + cur * 8192;

#define LOAD_AF16(m, XS) bf16x8 af##m = *(const bf16x8*)(const void*)(pa + abase + m * 1024 + XS);
#define LOAD_BF16(n, XS) bf16x8 bfr##n = *(const bf16x8*)(const void*)(pb + bbase + n * 1024 + XS);
      {
        LOAD_AF16(0, xs0) LOAD_AF16(1, xs0) LOAD_AF16(2, xs0) LOAD_AF16(3, xs0)
        LOAD_BF16(0, xs0) LOAD_BF16(1, xs0) LOAD_BF16(2, xs0) LOAD_BF16(3, xs0)
        FOR_MN(MFMA_OP)
      }
      {
        LOAD_AF16(0, xs1) LOAD_AF16(1, xs1) LOAD_AF16(2, xs1) LOAD_AF16(3, xs1)
        LOAD_BF16(0, xs1) LOAD_BF16(1, xs1) LOAD_BF16(2, xs1) LOAD_BF16(3, xs1)
        FOR_MN(MFMA_OP)
      }
#undef LOAD_AF16
#undef LOAD_BF16

      // all ds_reads of buf[cur] retired before t+1's stage overwrites it
      asm volatile("s_waitcnt lgkmcnt(0)" ::: "memory");
      __builtin_amdgcn_sched_barrier(0);
      __builtin_amdgcn_s_barrier();
      asm volatile("" ::: "memory");
    }
  } else {
    // ---- fp32 fallback: BK=32 double-buffer; A 128B rows (u ^= row&7),
    //      B 64B rows with parity swizzle ----
    const int srow32 = lane >> 3;
    const int scol32 = (((lane & 7) ^ srow32) * 4);  // floats
    const int srow16 = lane >> 2;
    const int scol16 = ((lane & 3) ^ ((lane >> 3) & 3)) * 8;  // shorts
    const float* gA32 =
        (const float*)Av + (size_t)(m0 + wave * 32 + srow32) * K_DIM + scol32;
    const unsigned short* gB16 =
        Wt + (size_t)(n0 + wave * 32 + srow16) * K_DIM + scol16;

    const int bxs = (quad ^ ((l16 >> 1) & 3)) * 8;
    const int bbase = (wn * 64 + l16) * 32;
    const int abasef = (wm * 64 + l16) * 32;
    const int u0 = ((2 * quad) ^ (l16 & 7)) * 4;
    const int u1 = ((2 * quad + 1) ^ (l16 & 7)) * 4;

    auto stage = [&](int d, int koff) {
      GLD16(gA32 + koff, lsAf + d * 4096 + wave * 1024);
      GLD16(gA32 + koff + 8 * K_DIM, lsAf + d * 4096 + wave * 1024 + 256);
      GLD16(gA32 + koff + 16 * K_DIM, lsAf + d * 4096 + wave * 1024 + 512);
      GLD16(gA32 + koff + 24 * K_DIM, lsAf + d * 4096 + wave * 1024 + 768);
      GLD16(gB16 + koff, lsB + d * 4096 + wave * 1024);
      GLD16(gB16 + (size_t)16 * K_DIM + koff, lsB + d * 4096 + wave * 1024 + 512);
    };

    constexpr int NT = K_DIM / 32;  // 64 K-tiles
    stage(0, 0);
    for (int t = 0; t < NT; ++t) {
      const int cur = t & 1;
      if (t + 1 < NT) {
        stage(cur ^ 1, (t + 1) * 32);
        asm volatile("s_waitcnt vmcnt(6)" ::: "memory");
      } else {
        asm volatile("s_waitcnt vmcnt(0)" ::: "memory");
      }
      __builtin_amdgcn_s_barrier();
      asm volatile("" ::: "memory");

      const float* paf = lsAf + cur * 4096;
      const unsigned short* pb = lsB + cur * 4096;

#define LOAD_AF32(m)                                                      \
      bf16x8 af##m;                                                       \
      { const float* ap_ = paf + abasef + m * 512;                        \
        f32x4 a0_ = *(const f32x4*)(ap_ + u0);                            \
        f32x4 a1_ = *(const f32x4*)(ap_ + u1);                            \
        af##m[0] = (__bf16)a0_[0]; af##m[1] = (__bf16)a0_[1];             \
        af##m[2] = (__bf16)a0_[2]; af##m[3] = (__bf16)a0_[3];             \
        af##m[4] = (__bf16)a1_[0]; af##m[5] = (__bf16)a1_[1];             \
        af##m[6] = (__bf16)a1_[2]; af##m[7] = (__bf16)a1_[3]; }
#define LOAD_BF32(n)                                                      \
      bf16x8 bfr##n = *(const bf16x8*)(const void*)(pb + bbase + n * 512 + bxs);

      LOAD_AF32(0) LOAD_AF32(1) LOAD_AF32(2) LOAD_AF32(3)
      LOAD_BF32(0) LOAD_BF32(1) LOAD_BF32(2) LOAD_BF32(3)
      FOR_MN(MFMA_OP)
#undef LOAD_AF32
#undef LOAD_BF32

      asm volatile("s_waitcnt lgkmcnt(0)" ::: "memory");
      __builtin_amdgcn_sched_barrier(0);
      __builtin_amdgcn_s_barrier();
      asm volatile("" ::: "memory");
    }
  }

  // ---- epilogue (all fp32); C/D layout: col = l16 (n), row = quad*4 + r (m) ----
  const int c_base = n0 + wn * 64;  // wave's 64 columns == one GroupNorm group
  const int t_base = (m0 & (T_DIM - 1)) + wm * 64;

#define LOADC(n)                                  \
  const int c##n = c_base + n * 16 + l16;         \
  const float hb##n = hhb[c##n];                  \
  const float gw##n = gnw[c##n];                  \
  const float gb##n = gnb[c##n];
  LOADC(0) LOADC(1) LOADC(2) LOADC(3)

  // rope on channels 0..63 (exactly the c_base==0 wave); pair partner is lane^1
  if (c_base == 0) {
#define ROPE_E(n,m,r)                                                   \
    { float v_ = a##m##n[r];                                            \
      float p_ = __shfl_xor(v_, 1, 64);                                 \
      int t_ = t_base + m * 16 + quad * 4 + r;                          \
      float ang_ = (float)t_ * fr_;                                     \
      float s_ = sinf(ang_);                                            \
      float co_ = cosf(ang_);                                           \
      a##m##n[r] = v_ * co_ + sg_ * p_ * s_; }
#define ROPE_M(n,m) ROPE_E(n,m,0) ROPE_E(n,m,1) ROPE_E(n,m,2) ROPE_E(n,m,3)
#define ROPE_N(n)                                                       \
    { int cc_ = n * 16 + l16;                                           \
      int ii_ = cc_ >> 1;                                               \
      float fr_ = expf(-(float)ii_ * 0.28782313662425572f);             \
      float sg_ = (cc_ & 1) ? 1.f : -1.f;                               \
      ROPE_M(n,0) ROPE_M(n,1) ROPE_M(n,2) ROPE_M(n,3) }
    ROPE_N(0) ROPE_N(1) ROPE_N(2) ROPE_N(3)
  }

  // relu -> +bias -> tanh -> GroupNorm (64-ch group == this wave's columns)
#define GN_ROW(m,r)                                                     \
  { float h0_ = tanhf(fmaxf(a##m##0[r], 0.f) + hb0);                    \
    float h1_ = tanhf(fmaxf(a##m##1[r], 0.f) + hb1);                    \
    float h2_ = tanhf(fmaxf(a##m##2[r], 0.f) + hb2);                    \
    float h3_ = tanhf(fmaxf(a##m##3[r], 0.f) + hb3);                    \
    float s1_ = h0_ + h1_ + h2_ + h3_;                                  \
    float s2_ = h0_ * h0_ + h1_ * h1_ + h2_ * h2_ + h3_ * h3_;          \
    s1_ += __shfl_xor(s1_, 1, 64);  s2_ += __shfl_xor(s2_, 1, 64);      \
    s1_ += __shfl_xor(s1_, 2, 64);  s2_ += __shfl_xor(s2_, 2, 64);      \
    s1_ += __shfl_xor(s1_, 4, 64);  s2_ += __shfl_xor(s2_, 4, 64);      \
    s1_ += __shfl_xor(s1_, 8, 64);  s2_ += __shfl_xor(s2_, 8, 64);      \
    float mu_ = s1_ * 0.015625f;                                        \
    float var_ = s2_ * 0.015625f - mu_ * mu_;                           \
    float rs_ = rsqrtf(var_ + 1e-5f);                                   \
    a##m##0[r] = (h0_ - mu_) * rs_ * gw0 + gb0;                         \
    a##m##1[r] = (h1_ - mu_) * rs_ * gw1 + gb1;                         \
    a##m##2[r] = (h2_ - mu_) * rs_ * gw2 + gb2;                         \
    a##m##3[r] = (h3_ - mu_) * rs_ * gw3 + gb3; }
#define GN_M(m) GN_ROW(m,0) GN_ROW(m,1) GN_ROW(m,2) GN_ROW(m,3)
  GN_M(0) GN_M(1) GN_M(2) GN_M(3)

  // ---- transposed store via LDS, two 64-row chunks (wm==h waves own chunk h) ----
  const int bb = m0 >> 12;          // batch
  const int t0 = m0 & (T_DIM - 1);  // t of block row 0
#define ST_MN(m,n)                                                      \
  lsO[wn * 64 + n * 16 + l16][m * 16 + quad * 4 + 0] = a##m##n[0];      \
  lsO[wn * 64 + n * 16 + l16][m * 16 + quad * 4 + 1] = a##m##n[1];      \
  lsO[wn * 64 + n * 16 + l16][m * 16 + quad * 4 + 2] = a##m##n[2];      \
  lsO[wn * 64 + n * 16 + l16][m * 16 + quad * 4 + 3] = a##m##n[3];
#pragma unroll
  for (int h = 0; h < 2; ++h) {
    if (wm == h) {
      FOR_MN(ST_MN)
    }
    __syncthreads();
    // 128 c x 64 t floats = 2048 float4 slots; each thread 8
#pragma unroll
    for (int i2 = 0; i2 < 8; ++i2) {
      int s = tid + i2 * 256;
      int cl = s >> 4;
      int t4 = (s & 15) * 4;
      float4 v = *(const float4*)&lsO[cl][t4];
      *(float4*)&out[(size_t)bb * C_DIM * T_DIM + (size_t)(n0 + cl) * T_DIM + t0 + h * 64 + t4] = v;
    }
    __syncthreads();  // before next chunk overwrites lsO
  }
}

// ---------------- S_n passthrough: (2,2048) fp32 after the big tensor ----------------
__global__ __launch_bounds__(256) void copy_sn(const float* __restrict__ src,
                                               float* __restrict__ dst) {
  int i = blockIdx.x * 256 + threadIdx.x;  // 0..4095
  dst[i] = src[i];
}

extern "C" void kernel_launch(void* const* d_in, const int* in_sizes, int n_in,
                              void* d_out, int out_size, void* d_ws, size_t ws_size,
                              hipStream_t stream) {
  const float* X = (const float*)d_in[0];
  const float* Sn = (const float*)d_in[1];
  const float* W = (const float*)d_in[2];
  const float* hhb = (const float*)d_in[3];
  const float* gnw = (const float*)d_in[4];
  const float* gnb = (const float*)d_in[5];
  float* out = (float*)d_out;

  // workspace layout: Wt bf16 [2048][2048] = 8 MB (always);
  // optional Xb bf16 [8192][2048] = 33.5 MB iff workspace is big enough.
  unsigned short* Wt = (unsigned short*)d_ws;
  const size_t wt_bytes = (size_t)C_DIM * K_DIM * 2;      // 8 MB
  const size_t xb_bytes = (size_t)2 * T_DIM * K_DIM * 2;  // 33.5 MB

  transpose_w<<<dim3(32, 32), dim3(256), 0, stream>>>(W, Wt);

  if (ws_size >= wt_bytes + xb_bytes) {
    unsigned short* Xb = Wt + (size_t)C_DIM * K_DIM;
    cvt_x<<<dim3(8192), dim3(256), 0, stream>>>(X, Xb);
    gemm_fused<true><<<dim3(1024), dim3(256), 0, stream>>>(Xb, Wt, hhb, gnw, gnb, out);
  } else {
    gemm_fused<false><<<dim3(1024), dim3(256), 0, stream>>>(X, Wt, hhb, gnw, gnb, out);
  }

  copy_sn<<<dim3(16), dim3(256), 0, stream>>>(Sn, out + (size_t)16777216);
}